// Round 5
// baseline (8414.406 us; speedup 1.0000x reference)
//
#include <hip/hip_runtime.h>
#include <hip/hip_bf16.h>
#include <stdint.h>

typedef unsigned short u16;
typedef __attribute__((ext_vector_type(8))) short bh8;
typedef __attribute__((ext_vector_type(4))) float f32x4;

static constexpr int Bv = 8, Tv = 2048, Cv = 1024;
#define SENT_BITS 0x7F800000u  // +inf: impossible h value since |h| < 1 strictly

__device__ inline u16 f2bf(float f) {
    unsigned u;
    __builtin_memcpy(&u, &f, 4);
    u = (u + 0x7fffu + ((u >> 16) & 1u)) >> 16;
    return (u16)u;
}
__device__ inline float bf2f(u16 v) {
    unsigned u = ((unsigned)v) << 16;
    float f;
    __builtin_memcpy(&f, &u, 4);
    return f;
}

// ---------------- elementwise convert x (fp32 -> bf16) ----------------
__global__ void cvt_x(const float* __restrict__ x, u16* __restrict__ xb, int n4) {
    int i = blockIdx.x * blockDim.x + threadIdx.x;
    if (i < n4) {
        float4 v = ((const float4*)x)[i];
        ushort4 o;
        o.x = f2bf(v.x); o.y = f2bf(v.y); o.z = f2bf(v.z); o.w = f2bf(v.w);
        ((ushort4*)xb)[i] = o;
    }
}

// ------------- transpose + convert 1024x1024 fp32 -> bf16 [n][k] -------------
__global__ void transpose_cvt(const float* __restrict__ W, u16* __restrict__ WT) {
    __shared__ float tile[32][33];
    int kb = blockIdx.x * 32, nb = blockIdx.y * 32;
    int tx = threadIdx.x, ty = threadIdx.y; // block (32,8)
#pragma unroll
    for (int r = 0; r < 32; r += 8)
        tile[ty + r][tx] = W[(size_t)(kb + ty + r) * 1024 + nb + tx];
    __syncthreads();
#pragma unroll
    for (int r = 0; r < 32; r += 8)
        WT[(size_t)(nb + ty + r) * 1024 + kb + tx] = f2bf(tile[tx][ty + r]);
}

// ---------------- bf16 MFMA GEMM: C[M,N] = A[M,K] * B[K,N], B given as BT[N,K] ----------------
template <bool OUT_BF16>
__global__ __launch_bounds__(256, 2) void gemm_bt(const u16* __restrict__ A,
                                                  const u16* __restrict__ BT,
                                                  void* __restrict__ Cout,
                                                  int M, int N, int K) {
    __shared__ uint4 As[2][1024]; // [row 0..127][slot 0..7] 16B granules, slot XOR-swizzled
    __shared__ uint4 Bs[2][1024];
    const int tid = threadIdx.x;
    const int lane = tid & 63;
    const int w = tid >> 6, wm = w >> 1, wn = w & 1;
    const int nTN = N >> 7;
    const int nwg = gridDim.x;
    const int q = nwg >> 3; // grid divisible by 8
    const int bid = blockIdx.x;
    const int swz = (bid & 7) * q + (bid >> 3); // XCD-contiguous chunks
    const int tm = swz / nTN, tn = swz % nTN;
    const size_t row0 = (size_t)tm * 128;
    const size_t col0 = (size_t)tn * 128;
    const int KT = K >> 6;

    uint4 ra[4], rb[4];

    auto issue_loads = [&](int kt) {
#pragma unroll
        for (int p = 0; p < 4; ++p) {
            int gi = p * 256 + tid;
            int r = gi >> 3, sl = gi & 7;
            ra[p] = *(const uint4*)(A + (row0 + r) * K + (size_t)kt * 64 + sl * 8);
            rb[p] = *(const uint4*)(BT + (col0 + r) * K + (size_t)kt * 64 + sl * 8);
        }
    };
    auto write_lds = [&](int bi) {
#pragma unroll
        for (int p = 0; p < 4; ++p) {
            int gi = p * 256 + tid;
            int r = gi >> 3, sl = gi & 7;
            int ph = sl ^ (r & 7);
            As[bi][r * 8 + ph] = ra[p];
            Bs[bi][r * 8 + ph] = rb[p];
        }
    };

    f32x4 acc[4][4];
#pragma unroll
    for (int m = 0; m < 4; ++m)
#pragma unroll
        for (int n = 0; n < 4; ++n)
            acc[m][n] = f32x4{0.f, 0.f, 0.f, 0.f};

    issue_loads(0);
    write_lds(0);
    int cur = 0;
    for (int kt = 0; kt < KT; ++kt) {
        if (kt + 1 < KT) issue_loads(kt + 1);
        __syncthreads();
#pragma unroll
        for (int s = 0; s < 2; ++s) {
            bh8 af[4], bfv[4];
#pragma unroll
            for (int m = 0; m < 4; ++m) {
                int ar = wm * 64 + m * 16 + (lane & 15);
                int sl = (s * 4 + (lane >> 4)) ^ (ar & 7);
                af[m] = __builtin_bit_cast(bh8, As[cur][ar * 8 + sl]);
            }
#pragma unroll
            for (int n = 0; n < 4; ++n) {
                int br = wn * 64 + n * 16 + (lane & 15);
                int sl = (s * 4 + (lane >> 4)) ^ (br & 7);
                bfv[n] = __builtin_bit_cast(bh8, Bs[cur][br * 8 + sl]);
            }
#pragma unroll
            for (int m = 0; m < 4; ++m)
#pragma unroll
                for (int n = 0; n < 4; ++n)
                    acc[m][n] = __builtin_amdgcn_mfma_f32_16x16x32_bf16(af[m], bfv[n], acc[m][n], 0, 0, 0);
        }
        if (kt + 1 < KT) write_lds(cur ^ 1);
        cur ^= 1;
    }
#pragma unroll
    for (int m = 0; m < 4; ++m) {
#pragma unroll
        for (int n = 0; n < 4; ++n) {
#pragma unroll
            for (int r = 0; r < 4; ++r) {
                size_t row = row0 + wm * 64 + m * 16 + (lane >> 4) * 4 + r;
                size_t col = col0 + wn * 64 + n * 16 + (lane & 15);
                float v = acc[m][n][r];
                if (OUT_BF16)
                    ((u16*)Cout)[row * N + col] = f2bf(v);
                else
                    ((float*)Cout)[row * N + col] = v;
            }
        }
    }
}

// ---------------- init B triple-buffer: buf0 = h0 = 0, buf1/buf2 = sentinel ----------------
__global__ void init_hbuf(unsigned* hbuf) {
    int i = blockIdx.x * 1024 + threadIdx.x; // 24 blocks x 1024 = 24576 words
    hbuf[i] = (i < 8192) ? 0u : SENT_BITS;
}

// ---------------- init one-shot A sequence in d_out: slice0 = 0, slices 1..2047 = SENT ----------------
__global__ void init_hA(uint4* hA4) {
    int i = blockIdx.x * 1024 + threadIdx.x; // 4096 blocks x 1024 = 4,194,304 uint4 = 64 MiB
    unsigned v = (i < 2048) ? 0u : SENT_BITS;
    hA4[i] = uint4{v, v, v, v};
}

// ---------------- sequential CfC scan ----------------
// 256 blocks x 1024 threads cooperative. block = (batch b = bid&7, col-group g = bid>>3).
// h exchange, two channels:
//   A (fast): ONE-SHOT fp32 slices hA[t][b][1024] in d_out; producer normal store (lands in
//     producer-XCD L2), consumer sc0 load (L1-bypass). One-shot => a stale-L2 hit can only
//     return SENTINEL (retry), never a wrong value — sound regardless of XCD placement.
//   B (guaranteed): R2-proven agent-scope triple-buffer in ws (always reaches L3).
// Consumer polls A 3x then B 1x, repeating. Producer publishes A and B only AFTER the
// vmcnt(0) that acks the bx-clear (so any consumer fast-forwarded by A still sees a
// cleared bx at t+2). Weights in 16 NAMED float4 registers (R2's VGPR_Count=48 showed
// wreg[64] was not register-resident).
__global__ __launch_bounds__(1024, 4) void cfc_scan(const float* __restrict__ Wf,
                                                    const float* __restrict__ Wg,
                                                    const u16* __restrict__ Pf,
                                                    const u16* __restrict__ Pg,
                                                    u16* __restrict__ H,
                                                    float* hbuf, float* hA) {
    const int bidx = blockIdx.x;
    const int b = bidx & 7, g = bidx >> 3;
    const int tid = threadIdx.x;
    const int w = tid >> 6;
    const int lane = tid & 63;
    const int slot = lane >> 4; // 0..3: {f(c0), g(c0), f(c1), g(c1)}
    const int sub = lane & 15;  // k-chunk owner within slot
    const int col = g * 32 + 2 * w + (slot >> 1);
    const bool isG = (slot & 1) != 0;
    // divergence-free activation constants: act = fma(1/(1+exp(cm*u)), sm, ofs)
    const float cm = isG ? -2.f : -1.f;
    const float sm = isG ? 2.f : 1.f;
    const float ofs = isG ? -1.f : 0.f;

    // ---- recurrent weights: 64 fp32 in 16 NAMED float4 registers ----
    const float* wb = (isG ? Wg : Wf) + (size_t)(1024 + sub * 4) * 1024 + col;
#define LDW(i) const float4 w##i = {wb[(size_t)((i)*64 + 0) * 1024], wb[(size_t)((i)*64 + 1) * 1024], \
                                    wb[(size_t)((i)*64 + 2) * 1024], wb[(size_t)((i)*64 + 3) * 1024]};
    LDW(0) LDW(1) LDW(2) LDW(3) LDW(4) LDW(5) LDW(6) LDW(7)
    LDW(8) LDW(9) LDW(10) LDW(11) LDW(12) LDW(13) LDW(14) LDW(15)
#undef LDW

    __shared__ __align__(16) float hs[2][1024]; // double-buffered staged h
    __shared__ u16 ps[2][64];                   // prefetched P values (f:0..31, g:32..63)

    // wave 0 prefetches P one step ahead (64 col-gates of this block)
    const u16* pptr = nullptr;
    u16 pcur = 0;
    if (w == 0) {
        const u16* pa = (lane < 32) ? Pf : Pg;
        pptr = pa + (size_t)b * Tv * Cv + g * 32 + (lane & 31);
        pcur = pptr[0];
    }

    const size_t hrow = (size_t)b * Tv * Cv + col;
    float* hb = hbuf + (size_t)b * 1024;                         // B triple-buffer (agent)
    const unsigned* abase = (const unsigned*)hA + b * 1024 + tid; // A one-shot poll addr
    unsigned* apub = (unsigned*)hA + b * 1024 + col;              // A one-shot publish addr
    int bc = 0, bn = 1, bx = 2; // B rotation: consume / publish / clear

    for (int t = 0; t < Tv; ++t) {
        // ---- poll own word: 3x A (sc0, L1-bypass) then 1x B (agent, L3), repeat ----
        const unsigned* asrc = abase + (size_t)t * 8192;
        const unsigned* bsrc = (const unsigned*)(hb + (size_t)bc * 8192) + tid;
        unsigned v;
        int spins = 0;
        while (true) {
            if ((spins & 3) != 3) {
                asm volatile("global_load_dword %0, %1, off sc0\n\ts_waitcnt vmcnt(0)"
                             : "=v"(v) : "v"(asrc) : "memory");
            } else {
                v = __hip_atomic_load(bsrc, __ATOMIC_RELAXED, __HIP_MEMORY_SCOPE_AGENT);
            }
            if (v != SENT_BITS) break;
            ++spins;
        }
        const int tb = t & 1;
        hs[tb][tid] = __builtin_bit_cast(float, v);
        if (w == 0) {
            ps[tb][lane] = pcur;                               // P[t] -> LDS
            if (t + 1 < Tv) pcur = pptr[(size_t)(t + 1) * Cv]; // issue P[t+1]
        }
        __syncthreads(); // the only barrier per step
        // ---- clear B buffer bx for reuse at t+2 (safe: h_t fully published => all blocks
        // finished reading h_{t-1}; ordered before our publishes by the vmcnt below) ----
        if ((lane & 31) == 0)
            __hip_atomic_store((unsigned*)(hb + (size_t)bx * 8192 + col), SENT_BITS,
                               __ATOMIC_RELAXED, __HIP_MEMORY_SCOPE_AGENT);
        // ---- fp32 matvec: 64 FMA in 4 independent chains, conflict-free LDS ----
        const float* hsrd = hs[tb];
        float ax = 0.f, ay = 0.f, az = 0.f, aw = 0.f;
#define MAC(i) { const float4 hv = *(const float4*)&hsrd[(i)*64 + sub * 4]; \
                 ax = fmaf(hv.x, w##i.x, ax); ay = fmaf(hv.y, w##i.y, ay);  \
                 az = fmaf(hv.z, w##i.z, az); aw = fmaf(hv.w, w##i.w, aw); }
        MAC(0) MAC(1) MAC(2) MAC(3) MAC(4) MAC(5) MAC(6) MAC(7)
        MAC(8) MAC(9) MAC(10) MAC(11) MAC(12) MAC(13) MAC(14) MAC(15)
#undef MAC
        float acc = (ax + ay) + (az + aw);
        acc += __shfl_xor(acc, 8);
        acc += __shfl_xor(acc, 4);
        acc += __shfl_xor(acc, 2);
        acc += __shfl_xor(acc, 1);
        float p = 0.f;
        if (sub == 0) p = bf2f(ps[tb][((slot & 1) << 5) + 2 * w + (slot >> 1)]);
        float u_ = acc + p;
        // divergence-free sigmoid/tanh: act = fma(1/(1+exp(cm*u)), sm, ofs)
        float act = fmaf(1.f / (1.f + __expf(cm * u_)), sm, ofs);
        float other = __shfl_xor(act, 16); // pair f(c) with g(c) in-wave
        if ((lane & 31) == 0) {
            float f_ = act, gv = other;
            float h_old = hsrd[col];
            float hnew = fmaf(f_, h_old - gv, gv);
            unsigned hbits = __builtin_bit_cast(unsigned, hnew);
            asm volatile("s_waitcnt vmcnt(0)" ::: "memory"); // bx-clear acked BEFORE publishes
            if (t + 1 < Tv)
                *(volatile unsigned*)(apub + (size_t)(t + 1) * 8192) = hbits; // A fast publish
            __hip_atomic_store((unsigned*)(hb + (size_t)bn * 8192 + col), hbits,
                               __ATOMIC_RELAXED, __HIP_MEMORY_SCOPE_AGENT);    // B publish
            H[hrow + (size_t)t * Cv] = f2bf(hnew);
        }
        int tmp = bc; bc = bn; bn = bx; bx = tmp;
    }
}

// ---------------- host launch ----------------
extern "C" void kernel_launch(void* const* d_in, const int* in_sizes, int n_in,
                              void* d_out, int out_size, void* d_ws, size_t ws_size,
                              hipStream_t stream) {
    const float* x  = (const float*)d_in[0];
    const float* Wf = (const float*)d_in[1];
    const float* Wg = (const float*)d_in[2];
    const float* Wp = (const float*)d_in[3];
    float* out = (float*)d_out;
    char* ws = (char*)d_ws;

    // workspace layout (bytes)
    u16*   xb    = (u16*)(ws + 0);          // 33554432 (dead after the two P-gemms)
    u16*   Pf    = (u16*)(ws + 33554432);   // 33554432
    u16*   Pg    = (u16*)(ws + 67108864);   // 33554432
    u16*   Hb    = (u16*)(ws + 100663296);  // 33554432
    u16*   WfT   = (u16*)(ws + 134217728);  // 2097152
    u16*   WgT   = (u16*)(ws + 136314880);  // 2097152
    u16*   WpT   = (u16*)(ws + 138412032);  // 2097152
    // B triple-buffer reuses the (dead) xb region: 3 x 8 x 1024 fp32 = 98304 B
    float* hbuf  = (float*)(ws + 0);
    // A one-shot sequence lives in d_out (64 MiB = 2048 slices x 8 x 1024 fp32),
    // dead scratch until the final GEMM overwrites it.
    float* hA    = out;

    cvt_x<<<16384, 256, 0, stream>>>(x, xb, (Bv * Tv * Cv) / 4);

    dim3 tg(32, 32), tb(32, 8);
    transpose_cvt<<<tg, tb, 0, stream>>>(Wf, WfT); // top half rows of W_f
    transpose_cvt<<<tg, tb, 0, stream>>>(Wg, WgT);
    transpose_cvt<<<tg, tb, 0, stream>>>(Wp, WpT);

    gemm_bt<true><<<1024, 256, 0, stream>>>(xb, WfT, (void*)Pf, Bv * Tv, Cv, Cv);
    gemm_bt<true><<<1024, 256, 0, stream>>>(xb, WgT, (void*)Pg, Bv * Tv, Cv, Cv);

    // xb now dead; initialize B triple-buffer in its place, and A one-shot seq in d_out
    init_hbuf<<<24, 1024, 0, stream>>>((unsigned*)hbuf);
    init_hA<<<4096, 1024, 0, stream>>>((uint4*)hA);

    {
        const float* a0 = Wf;
        const float* a1 = Wg;
        const u16* a2 = Pf;
        const u16* a3 = Pg;
        u16* a4 = Hb;
        float* a5 = hbuf;
        float* a6 = hA;
        void* args[] = {(void*)&a0, (void*)&a1, (void*)&a2, (void*)&a3,
                        (void*)&a4, (void*)&a5, (void*)&a6};
        hipLaunchCooperativeKernel((const void*)cfc_scan, dim3(256), dim3(1024), args, 0, stream);
    }

    gemm_bt<false><<<1024, 256, 0, stream>>>(Hb, WpT, (void*)out, Bv * Tv, Cv, Cv);
}